// Round 1
// baseline (774.594 us; speedup 1.0000x reference)
//
#include <hip/hip_runtime.h>
#include <cmath>

// NPHierarchicalTransitionPrior: per-sample tiny-MLP forward + input-gradient.
// One thread = one (sample n, unit d) pair. Weights staged in LDS (wave-uniform
// broadcast reads). leaky' stored as 64-bit sign masks. f32 throughout.

namespace {

constexpr int NB    = 256;        // batch
constexpr int NT    = 512;        // output time steps (T - LAGS)
constexpr int TROW  = 513;        // input time steps
constexpr int NSAMP = NB * NT;    // 131072
constexpr int DIN   = 16;
constexpr int HID   = 64;

constexpr size_t OFF_SUMLOG = (size_t)NSAMP * DIN;            // 2097152
constexpr size_t OFF_H0     = OFF_SUMLOG + NB;                // 2097408
constexpr size_t OFF_H1     = OFF_H0 + (size_t)8 * NSAMP * 8; // 10486016

__global__ void zero_sumlog_kernel(float* __restrict__ out) {
    out[OFF_SUMLOG + threadIdx.x] = 0.0f;
}

template<int L, int IN_DIM>
__global__ __launch_bounds__(256) void mlp_fwdbwd_kernel(
        const float* __restrict__ x,
        const float* __restrict__ gW1, const float* __restrict__ gb1,
        const float* __restrict__ gW2, const float* __restrict__ gb2,
        const float* __restrict__ gW3, const float* __restrict__ gb3,
        float* __restrict__ out)
{
    __shared__ float sW1[HID * IN_DIM];
    __shared__ float sb1[HID];
    __shared__ float sW2[HID * HID];
    __shared__ float sb2[HID];
    __shared__ float sW3[HID];
    __shared__ float sb3s[1];
    __shared__ float red[4];

    const int d   = blockIdx.x >> 9;          // unit 0..7
    const int tid = threadIdx.x;
    const int n   = ((blockIdx.x & 511) << 8) | tid;   // sample 0..131071

    // ---- stage this unit's weights into LDS
    {
        const float* w1 = gW1 + d * HID * IN_DIM;
        for (int i = tid; i < HID * IN_DIM; i += 256) sW1[i] = w1[i];
        const float* w2 = gW2 + d * HID * HID;
        for (int i = tid; i < HID * HID; i += 256) sW2[i] = w2[i];
        if (tid < HID) {
            sb1[tid] = gb1[d * HID + tid];
            sb2[tid] = gb2[d * HID + tid];
            sW3[tid] = gW3[d * HID + tid];
        }
        if (tid == 0) sb3s[0] = gb3[d];
    }
    __syncthreads();

    // ---- gather this sample's MLP input vector
    // yy = x[b, t, :], xx = x[b, t+1, :], n = b*512 + t
    const float* yyp = x + ((size_t)(n >> 9) * TROW + (size_t)(n & 511)) * DIN;
    const float* xxp = yyp + DIN;
    float v[IN_DIM];
    if constexpr (L == 0) {
        // inputs = [yy[8:16], xx[8+d]]
        float4 a = *reinterpret_cast<const float4*>(yyp + 8);
        float4 b = *reinterpret_cast<const float4*>(yyp + 12);
        v[0]=a.x; v[1]=a.y; v[2]=a.z; v[3]=a.w;
        v[4]=b.x; v[5]=b.y; v[6]=b.z; v[7]=b.w;
        v[8] = xxp[8 + d];
    } else {
        // inputs = [yy[0:8], xx[8:16], xx[d]]
        float4 a = *reinterpret_cast<const float4*>(yyp);
        float4 b = *reinterpret_cast<const float4*>(yyp + 4);
        float4 c = *reinterpret_cast<const float4*>(xxp + 8);
        float4 e = *reinterpret_cast<const float4*>(xxp + 12);
        v[0]=a.x;  v[1]=a.y;  v[2]=a.z;  v[3]=a.w;
        v[4]=b.x;  v[5]=b.y;  v[6]=b.z;  v[7]=b.w;
        v[8]=c.x;  v[9]=c.y;  v[10]=c.z; v[11]=c.w;
        v[12]=e.x; v[13]=e.y; v[14]=e.z; v[15]=e.w;
        v[16] = xxp[d];
    }

    // ---- layer 1 forward: h1 = leaky(W1 v + b1), mask m1 = (pre >= 0)
    float h1[HID];
    unsigned long long m1 = 0ull;
    #pragma unroll
    for (int k = 0; k < HID; ++k) {
        float t0 = sb1[k];
        #pragma unroll
        for (int i = 0; i < IN_DIM; ++i) t0 = fmaf(sW1[k * IN_DIM + i], v[i], t0);
        bool p = (t0 >= 0.0f);
        m1 |= (unsigned long long)p << k;
        h1[k] = p ? t0 : 0.01f * t0;
    }

    // ---- layer 2 forward + scalar output: out = W3 leaky(W2 h1 + b2) + b3
    float acc_out = sb3s[0];
    unsigned long long m2 = 0ull;
    #pragma unroll 4
    for (int j = 0; j < HID; ++j) {
        float t0 = sb2[j];
        #pragma unroll
        for (int k = 0; k < HID; ++k) t0 = fmaf(sW2[j * HID + k], h1[k], t0);
        bool p = (t0 >= 0.0f);
        m2 |= (unsigned long long)p << j;
        acc_out = fmaf(sW3[j], p ? t0 : 0.01f * t0, acc_out);
    }

    // ---- backward: u1 = W2^T (D2 * W3^T)   (h1 dead; u1 reuses its regs)
    float u1[HID];
    #pragma unroll
    for (int k = 0; k < HID; ++k) u1[k] = 0.0f;
    #pragma unroll 4
    for (int j = 0; j < HID; ++j) {
        float u2j = sW3[j] * ((((m2 >> j) & 1ull) != 0ull) ? 1.0f : 0.01f);
        #pragma unroll
        for (int k = 0; k < HID; ++k) u1[k] = fmaf(sW2[j * HID + k], u2j, u1[k]);
    }
    #pragma unroll
    for (int k = 0; k < HID; ++k)
        u1[k] *= ((((m1 >> k) & 1ull) != 0ull) ? 1.0f : 0.01f);

    // ---- grad = W1^T u1
    float g[IN_DIM];
    #pragma unroll
    for (int i = 0; i < IN_DIM; ++i) {
        float acc = 0.0f;
        #pragma unroll
        for (int k = 0; k < HID; ++k) acc = fmaf(sW1[k * IN_DIM + i], u1[k], acc);
        g[i] = acc;
    }

    // ---- stores
    out[(size_t)n * DIN + L * 8 + d] = acc_out;   // residuals (N,16)
    if constexpr (L == 0) {
        float* hp = out + OFF_H0 + ((size_t)d * NSAMP + (size_t)n) * 8;
        *reinterpret_cast<float4*>(hp)     = make_float4(g[0], g[1], g[2], g[3]);
        *reinterpret_cast<float4*>(hp + 4) = make_float4(g[4], g[5], g[6], g[7]);
    } else {
        float* hp = out + OFF_H1 + ((size_t)d * NSAMP + (size_t)n) * 16;
        *reinterpret_cast<float4*>(hp)      = make_float4(g[0],  g[1],  g[2],  g[3]);
        *reinterpret_cast<float4*>(hp + 4)  = make_float4(g[4],  g[5],  g[6],  g[7]);
        *reinterpret_cast<float4*>(hp + 8)  = make_float4(g[8],  g[9],  g[10], g[11]);
        *reinterpret_cast<float4*>(hp + 12) = make_float4(g[12], g[13], g[14], g[15]);
    }

    // ---- logdet: sum log|d out / d xcol| over (l, d) per sample, then per batch
    float lg = logf(fabsf(g[IN_DIM - 1]));
    #pragma unroll
    for (int off = 32; off > 0; off >>= 1) lg += __shfl_down(lg, off, 64);
    if ((tid & 63) == 0) red[tid >> 6] = lg;
    __syncthreads();
    if (tid == 0) {
        atomicAdd(out + OFF_SUMLOG + (size_t)(n >> 9),
                  red[0] + red[1] + red[2] + red[3]);
    }
}

} // namespace

extern "C" void kernel_launch(void* const* d_in, const int* in_sizes, int n_in,
                              void* d_out, int out_size, void* d_ws, size_t ws_size,
                              hipStream_t stream) {
    const float* x     = (const float*)d_in[0];
    // d_in[1] = alphas — unused by the reference outputs
    const float* l0_W1 = (const float*)d_in[2];
    const float* l0_b1 = (const float*)d_in[3];
    const float* l0_W2 = (const float*)d_in[4];
    const float* l0_b2 = (const float*)d_in[5];
    const float* l0_W3 = (const float*)d_in[6];
    const float* l0_b3 = (const float*)d_in[7];
    const float* l1_W1 = (const float*)d_in[8];
    const float* l1_b1 = (const float*)d_in[9];
    const float* l1_W2 = (const float*)d_in[10];
    const float* l1_b2 = (const float*)d_in[11];
    const float* l1_W3 = (const float*)d_in[12];
    const float* l1_b3 = (const float*)d_in[13];
    float* out = (float*)d_out;

    zero_sumlog_kernel<<<1, 256, 0, stream>>>(out);
    mlp_fwdbwd_kernel<0, 9><<<4096, 256, 0, stream>>>(
        x, l0_W1, l0_b1, l0_W2, l0_b2, l0_W3, l0_b3, out);
    mlp_fwdbwd_kernel<1, 17><<<4096, 256, 0, stream>>>(
        x, l1_W1, l1_b1, l1_W2, l1_b2, l1_W3, l1_b3, out);
}

// Round 2
// 191.853 us; speedup vs baseline: 4.0374x; 4.0374x over previous
//
#include <hip/hip_runtime.h>
#include <cmath>

// NPHierarchicalTransitionPrior — MFMA formulation.
// Per block: one (layer, unit d, batch row b); 8 passes x 64 samples.
// GEMM1: H1pre = W1 (64xIN,pad32) x V (32x64)          [M-split across 4 waves]
// GEMM2: H2pre = W2 (64x64) x H1 (64x64)               [M-split]
// GEMM3: U1    = W2^T (64x64) x U2 (64x64)             [M-split]
// GEMM4: G     = W1^T (INx64,pad) x (D1.U1) (64x64)    [N-split]
// Hand-off via LDS in B-fragment-native layout: addr(k,n)=((k>>3)*64+n)*16+(k&7)*2.

namespace {

using bf16x8 = __attribute__((ext_vector_type(8))) short;
using f32x4  = __attribute__((ext_vector_type(4))) float;

constexpr int NB = 256, NT = 512, TROW = 513, DIN = 16, HID = 64;
constexpr int NSAMP = NB * NT;                              // 131072
constexpr size_t OFF_SUMLOG = (size_t)NSAMP * DIN;          // 2097152
constexpr size_t OFF_H0     = OFF_SUMLOG + NB;              // 2097408
constexpr size_t OFF_H1     = OFF_H0 + (size_t)8 * NSAMP * 8; // 10486016

struct SMem {
    alignas(16) char H1[8192];   // bf16 64k x 64n, frag-native
    alignas(16) char U2[8192];
    alignas(16) char U1[8192];
    float sresW[256];            // per-wave residual partials [w][n]
    float slogW[4];
};

__device__ __forceinline__ short f2bf(float f) {            // RNE f32->bf16
    unsigned u = __builtin_bit_cast(unsigned, f);
    u += 0x7FFFu + ((u >> 16) & 1u);
    return (short)(u >> 16);
}
__device__ __forceinline__ unsigned pk2(float a, float b) {
    return (unsigned)(unsigned short)f2bf(a) | ((unsigned)(unsigned short)f2bf(b) << 16);
}
// read B-frag: elements k=(4*ks+q)*8+e, column n   (lane-consecutive 16B -> conflict-free)
__device__ __forceinline__ bf16x8 rdfrag(const char* buf, int ks, int q, int n) {
    return *reinterpret_cast<const bf16x8*>(buf + ((((ks << 2) + q) * 64 + n) << 4));
}
// write 4 consecutive-k bf16 values (k0..k0+3, k0%4==0) at column n (one ds_write_b64)
__device__ __forceinline__ void wrquad(char* buf, int k0, int n,
                                       float a, float b, float c, float d) {
    uint2 v; v.x = pk2(a, b); v.y = pk2(c, d);
    *reinterpret_cast<uint2*>(buf + (((k0 >> 3) * 64 + n) << 4) + ((k0 & 7) << 1)) = v;
}
__device__ __forceinline__ f32x4 mfma16(bf16x8 a, bf16x8 b, f32x4 c) {
    return __builtin_amdgcn_mfma_f32_16x16x32_bf16(a, b, c, 0, 0, 0);
}

template<int L, int IN>
__device__ __forceinline__ void mlp_impl(
    SMem& sm, int bid,
    const float* __restrict__ x,
    const float* __restrict__ gW1, const float* __restrict__ gb1,
    const float* __restrict__ gW2, const float* __restrict__ gb2,
    const float* __restrict__ gW3, const float* __restrict__ gb3,
    float* __restrict__ out)
{
    const int tid  = threadIdx.x;
    const int w    = tid >> 6, lane = tid & 63;
    const int q    = lane >> 4, r = lane & 15;
    const int d    = bid & 7, b = bid >> 3;

    // ---- hoist A-fragments + consts to registers (once per block)
    bf16x8 aW1;  // A[j=16w+r][k=8q+e] of W1 (zero-padded past IN)
    {
        const float* p = gW1 + (size_t)(d * HID + 16 * w + r) * IN;
        #pragma unroll
        for (int e = 0; e < 8; ++e) {
            int k = 8 * q + e;
            aW1[e] = (k < IN) ? f2bf(p[k]) : (short)0;
        }
    }
    bf16x8 aW2[2], aW2T[2];
    #pragma unroll
    for (int ks = 0; ks < 2; ++ks) {
        const float* p = gW2 + (size_t)(d * HID + 16 * w + r) * HID + 32 * ks + 8 * q;
        #pragma unroll
        for (int e = 0; e < 8; ++e) aW2[ks][e] = f2bf(p[e]);
        const float* pt = gW2 + (size_t)d * HID * HID
                        + (size_t)(32 * ks + 8 * q) * HID + 16 * w + r;
        #pragma unroll
        for (int e = 0; e < 8; ++e) aW2T[ks][e] = f2bf(pt[(size_t)e * HID]);
    }
    constexpr int NMT = (IN > 16) ? 2 : 1;
    bf16x8 aW1T[NMT][2];  // A[i=16mt+r][k=8q+e+32ks] of W1^T
    #pragma unroll
    for (int mt = 0; mt < NMT; ++mt) {
        const int i = 16 * mt + r;
        #pragma unroll
        for (int ks = 0; ks < 2; ++ks) {
            const float* pt = gW1 + (size_t)d * HID * IN
                            + (size_t)(32 * ks + 8 * q) * IN + i;
            #pragma unroll
            for (int e = 0; e < 8; ++e)
                aW1T[mt][ks][e] = (i < IN) ? f2bf(pt[(size_t)e * IN]) : (short)0;
        }
    }
    const f32x4 c1init = *reinterpret_cast<const f32x4*>(gb1 + d * HID + 16 * w + 4 * q);
    const f32x4 c2init = *reinterpret_cast<const f32x4*>(gb2 + d * HID + 16 * w + 4 * q);
    const f32x4 w3r    = *reinterpret_cast<const f32x4*>(gW3 + d * HID + 16 * w + 4 * q);
    const float b3v = gb3[d];

    const float* xb = x + (size_t)b * TROW * DIN;
    float lgacc = 0.0f;

    for (int ps = 0; ps < 8; ++ps) {
        const int tbase = ps * 64;
        unsigned m1 = 0;

        // ---- GEMM1: H1pre = W1 V + b1 ; leaky -> H1(LDS), mask m1
        #pragma unroll
        for (int g = 0; g < 4; ++g) {
            const float* xr = xb + (size_t)(tbase + 16 * g + r) * DIN;
            float f[8] = {0, 0, 0, 0, 0, 0, 0, 0};
            if constexpr (L == 0) {
                if (q == 0) {                 // yy[8..15]
                    f32x4 u0 = *reinterpret_cast<const f32x4*>(xr + 8);
                    f32x4 u1 = *reinterpret_cast<const f32x4*>(xr + 12);
                    f[0]=u0[0]; f[1]=u0[1]; f[2]=u0[2]; f[3]=u0[3];
                    f[4]=u1[0]; f[5]=u1[1]; f[6]=u1[2]; f[7]=u1[3];
                } else if (q == 1) {          // xx[8+d]
                    f[0] = xr[DIN + 8 + d];
                }
            } else {
                if (q == 0) {                 // yy[0..7]
                    f32x4 u0 = *reinterpret_cast<const f32x4*>(xr);
                    f32x4 u1 = *reinterpret_cast<const f32x4*>(xr + 4);
                    f[0]=u0[0]; f[1]=u0[1]; f[2]=u0[2]; f[3]=u0[3];
                    f[4]=u1[0]; f[5]=u1[1]; f[6]=u1[2]; f[7]=u1[3];
                } else if (q == 1) {          // xx[8..15]
                    f32x4 u0 = *reinterpret_cast<const f32x4*>(xr + 24);
                    f32x4 u1 = *reinterpret_cast<const f32x4*>(xr + 28);
                    f[0]=u0[0]; f[1]=u0[1]; f[2]=u0[2]; f[3]=u0[3];
                    f[4]=u1[0]; f[5]=u1[1]; f[6]=u1[2]; f[7]=u1[3];
                } else if (q == 2) {          // xx[d]
                    f[0] = xr[DIN + d];
                }
            }
            bf16x8 bv;
            #pragma unroll
            for (int e = 0; e < 8; ++e) bv[e] = f2bf(f[e]);
            f32x4 acc = mfma16(aW1, bv, c1init);
            float h[4];
            #pragma unroll
            for (int e = 0; e < 4; ++e) {
                bool p = acc[e] >= 0.0f;
                m1 |= (unsigned)p << (g * 4 + e);
                h[e] = p ? acc[e] : 0.01f * acc[e];
            }
            wrquad(sm.H1, 16 * w + 4 * q, 16 * g + r, h[0], h[1], h[2], h[3]);
        }
        __syncthreads();

        // ---- GEMM2: H2pre = W2 H1 + b2 ; residual partial + U2(LDS)
        #pragma unroll
        for (int g = 0; g < 4; ++g) {
            f32x4 acc = c2init;
            acc = mfma16(aW2[0], rdfrag(sm.H1, 0, q, 16 * g + r), acc);
            acc = mfma16(aW2[1], rdfrag(sm.H1, 1, q, 16 * g + r), acc);
            float pr = 0.0f, u2v[4];
            #pragma unroll
            for (int e = 0; e < 4; ++e) {
                bool p = acc[e] >= 0.0f;
                float h2 = p ? acc[e] : 0.01f * acc[e];
                pr = fmaf(w3r[e], h2, pr);
                u2v[e] = p ? w3r[e] : 0.01f * w3r[e];
            }
            pr += __shfl_xor(pr, 16, 64);
            pr += __shfl_xor(pr, 32, 64);
            if (q == 0) sm.sresW[w * 64 + 16 * g + r] = pr;
            wrquad(sm.U2, 16 * w + 4 * q, 16 * g + r, u2v[0], u2v[1], u2v[2], u2v[3]);
        }
        __syncthreads();

        // ---- GEMM3: U1 = W2^T U2 ; mask by m1 -> U1m(LDS)
        #pragma unroll
        for (int g = 0; g < 4; ++g) {
            f32x4 acc = {0.0f, 0.0f, 0.0f, 0.0f};
            acc = mfma16(aW2T[0], rdfrag(sm.U2, 0, q, 16 * g + r), acc);
            acc = mfma16(aW2T[1], rdfrag(sm.U2, 1, q, 16 * g + r), acc);
            float u1v[4];
            #pragma unroll
            for (int e = 0; e < 4; ++e)
                u1v[e] = acc[e] * (((m1 >> (g * 4 + e)) & 1u) ? 1.0f : 0.01f);
            wrquad(sm.U1, 16 * w + 4 * q, 16 * g + r, u1v[0], u1v[1], u1v[2], u1v[3]);
        }
        __syncthreads();

        // ---- GEMM4 (N-split: wave w owns samples n=16w+r): G = W1^T U1m
        {
            const int nloc = tbase + 16 * w + r;
            const size_t nglob = (size_t)b * NT + nloc;
            bf16x8 bu0 = rdfrag(sm.U1, 0, q, 16 * w + r);
            bf16x8 bu1 = rdfrag(sm.U1, 1, q, 16 * w + r);
            f32x4 g0 = {0.0f, 0.0f, 0.0f, 0.0f};
            g0 = mfma16(aW1T[0][0], bu0, g0);
            g0 = mfma16(aW1T[0][1], bu1, g0);
            if constexpr (L == 1) {
                f32x4 g1 = {0.0f, 0.0f, 0.0f, 0.0f};
                g1 = mfma16(aW1T[1][0], bu0, g1);
                g1 = mfma16(aW1T[1][1], bu1, g1);
                float* hp = out + OFF_H1 + ((size_t)d * NSAMP + nglob) * 16 + 4 * q;
                *reinterpret_cast<f32x4*>(hp) = g0;
                if (q == 0) lgacc += logf(fabsf(g1[0]));   // row i=16 (xcol)
            } else {
                if (q < 2) {
                    float* hp = out + OFF_H0 + ((size_t)d * NSAMP + nglob) * 8 + 4 * q;
                    *reinterpret_cast<f32x4*>(hp) = g0;
                }
                if (q == 2) lgacc += logf(fabsf(g0[0]));   // row i=8 (xcol)
            }
        }
        // ---- residual store (sresW complete since the U2 barrier)
        if (tid < 64) {
            float rs = sm.sresW[tid] + sm.sresW[64 + tid]
                     + sm.sresW[128 + tid] + sm.sresW[192 + tid] + b3v;
            out[((size_t)b * NT + tbase + tid) * DIN + L * 8 + d] = rs;
        }
        // next pass's first write to H1 is fenced by its own barrier #1;
        // sresW rewrite is also after that barrier -> no extra barrier here.
    }

    // ---- block epilogue: logdet reduction + one global atomic per block
    float v = lgacc;
    #pragma unroll
    for (int off = 1; off < 64; off <<= 1) v += __shfl_xor(v, off, 64);
    if (lane == 0) sm.slogW[w] = v;
    __syncthreads();
    if (tid == 0)
        atomicAdd(out + OFF_SUMLOG + b, sm.slogW[0] + sm.slogW[1] + sm.slogW[2] + sm.slogW[3]);
}

__global__ void zero_sumlog_kernel(float* __restrict__ out) {
    out[OFF_SUMLOG + threadIdx.x] = 0.0f;
}

__global__ __launch_bounds__(256, 3) void mlp_mfma_kernel(
    const float* __restrict__ x,
    const float* __restrict__ l0W1, const float* __restrict__ l0b1,
    const float* __restrict__ l0W2, const float* __restrict__ l0b2,
    const float* __restrict__ l0W3, const float* __restrict__ l0b3,
    const float* __restrict__ l1W1, const float* __restrict__ l1b1,
    const float* __restrict__ l1W2, const float* __restrict__ l1b2,
    const float* __restrict__ l1W3, const float* __restrict__ l1b3,
    float* __restrict__ out)
{
    __shared__ SMem sm;
    if (blockIdx.x < 2048)
        mlp_impl<0, 9>(sm, blockIdx.x, x, l0W1, l0b1, l0W2, l0b2, l0W3, l0b3, out);
    else
        mlp_impl<1, 17>(sm, blockIdx.x - 2048, x, l1W1, l1b1, l1W2, l1b2, l1W3, l1b3, out);
}

} // namespace

extern "C" void kernel_launch(void* const* d_in, const int* in_sizes, int n_in,
                              void* d_out, int out_size, void* d_ws, size_t ws_size,
                              hipStream_t stream) {
    const float* x = (const float*)d_in[0];
    // d_in[1] = alphas — unused by the reference outputs
    float* out = (float*)d_out;

    zero_sumlog_kernel<<<1, 256, 0, stream>>>(out);
    mlp_mfma_kernel<<<4096, 256, 0, stream>>>(
        x,
        (const float*)d_in[2],  (const float*)d_in[3],  (const float*)d_in[4],
        (const float*)d_in[5],  (const float*)d_in[6],  (const float*)d_in[7],
        (const float*)d_in[8],  (const float*)d_in[9],  (const float*)d_in[10],
        (const float*)d_in[11], (const float*)d_in[12], (const float*)d_in[13],
        out);
}

// Round 3
// 148.720 us; speedup vs baseline: 5.2084x; 1.2900x over previous
//
#include <hip/hip_runtime.h>
#include <hip/hip_bf16.h>
#include <cmath>

// NPHierarchicalTransitionPrior — MFMA formulation, round 3.
// Block = one (layer L, unit d, batch row b); 8 passes x 64 samples.
//   GEMM1: H1pre = W1 (64xIN pad32) x V(32x64)   [M-split over 4 waves]
//   GEMM2: H2pre = W2 (64x64) x H1               [M-split]
//   GEMM3: U1    = W2^T x U2                     [M-split]
//   GEMM4: G     = W1^T x (D1.U1)                [N-split]
// LDS hand-off in B-frag-native layout, XOR-swizzled:
//   byte(k,n) = (k>>3)*1024 + n*16 + (k&7)*2, then bits[6:4] ^= ((k>>3)&3)<<1 ^ ((n>>3)&1)
//   -> ds_read_b128 conflict-free, ds_write_b64 2-way (free).
// XCD-aware block decode: xcd owns 32 batch rows -> x + residual lines stay in one L2.

namespace {

using bf16x8 = __attribute__((ext_vector_type(8))) short;
using f32x4  = __attribute__((ext_vector_type(4))) float;
using f32x2  = __attribute__((ext_vector_type(2))) float;
using bf2    = __attribute__((ext_vector_type(2))) __bf16;
using u32x2  = __attribute__((ext_vector_type(2))) unsigned;
using u32x4  = __attribute__((ext_vector_type(4))) unsigned;

constexpr int NB = 256, NT = 512, TROW = 513, DIN = 16, HID = 64;
constexpr int NSAMP = NB * NT;                                // 131072
constexpr size_t OFF_SUMLOG = (size_t)NSAMP * DIN;            // 2097152
constexpr size_t OFF_H0     = OFF_SUMLOG + NB;                // 2097408
constexpr size_t OFF_H1     = OFF_H0 + (size_t)8 * NSAMP * 8; // 10486016

struct SMem {
    alignas(16) char frag[3 * 8192];   // H1 | U2 | U1m  (bf16, frag-native, swizzled)
    float sresW[256];                  // per-wave residual partials [w][n]
    float slogW[4];
};

__device__ __forceinline__ short b16(float f) {
    return __builtin_bit_cast(short, (__bf16)f);
}
// pair convert -> v_cvt_pk_bf16_f32
__device__ __forceinline__ unsigned pk2(float a, float b) {
    f32x2 t{a, b};
    return __builtin_bit_cast(unsigned, __builtin_convertvector(t, bf2));
}
__device__ __forceinline__ bf16x8 mkfrag(unsigned a, unsigned b, unsigned c, unsigned d) {
    u32x4 t{a, b, c, d};
    return __builtin_bit_cast(bf16x8, t);
}
__device__ __forceinline__ f32x4 mfma16(bf16x8 a, bf16x8 b, f32x4 c) {
    return __builtin_amdgcn_mfma_f32_16x16x32_bf16(a, b, c, 0, 0, 0);
}

template<int L, int IN>
__device__ __forceinline__ void mlp_impl(
    SMem& sm, int d, int b,
    const float* __restrict__ x,
    const float* __restrict__ gW1, const float* __restrict__ gb1,
    const float* __restrict__ gW2, const float* __restrict__ gb2,
    const float* __restrict__ gW3, const float* __restrict__ gb3,
    float* __restrict__ out)
{
    const int tid = threadIdx.x;
    const int w = tid >> 6, lane = tid & 63;
    const int q = lane >> 4, r = lane & 15;

    // ---- swizzled LDS byte bases (constant per thread)
    // reads: element k=32ks+8q+e, col n=16g+r  ->  rbase + ks*4096 + g*256 (+buf)
    const int rbase = (q * 1024 + r * 16)
                    ^ ((((q & 3) << 1) ^ ((r >> 3) & 1)) << 4);
    // writes: rows k0=16w+4q..+3, col n=16g+r  ->  wbase + g*256 (+buf)
    const int q4w = 2 * w + (q >> 1);
    const int wbase = (q4w * 1024 + r * 16 + (q & 1) * 8)
                    ^ ((((q4w & 3) << 1) ^ ((r >> 3) & 1)) << 4);
    char* fr = sm.frag;

    // ---- hoist A-fragments + consts to registers (once per block)
    bf16x8 aW1;  // A[j=16w+r][k=8q+e] of W1, zero-padded past IN
    {
        const float* p = gW1 + (size_t)(d * HID + 16 * w + r) * IN;
        #pragma unroll
        for (int e = 0; e < 8; ++e) {
            int k = 8 * q + e;
            aW1[e] = (k < IN) ? b16(p[k]) : (short)0;
        }
    }
    bf16x8 aW2[2], aW2T[2];
    #pragma unroll
    for (int ks = 0; ks < 2; ++ks) {
        const float* p = gW2 + (size_t)(d * HID + 16 * w + r) * HID + 32 * ks + 8 * q;
        #pragma unroll
        for (int e = 0; e < 8; ++e) aW2[ks][e] = b16(p[e]);
        const float* pt = gW2 + (size_t)d * HID * HID
                        + (size_t)(32 * ks + 8 * q) * HID + 16 * w + r;
        #pragma unroll
        for (int e = 0; e < 8; ++e) aW2T[ks][e] = b16(pt[(size_t)e * HID]);
    }
    constexpr int NMT = (IN > 16) ? 2 : 1;
    bf16x8 aW1T[NMT][2];  // A[i=16mt+r][k=8q+e+32ks] of W1^T
    #pragma unroll
    for (int mt = 0; mt < NMT; ++mt) {
        const int i = 16 * mt + r;
        #pragma unroll
        for (int ks = 0; ks < 2; ++ks) {
            const float* pt = gW1 + (size_t)d * HID * IN
                            + (size_t)(32 * ks + 8 * q) * IN + i;
            #pragma unroll
            for (int e = 0; e < 8; ++e)
                aW1T[mt][ks][e] = (i < IN) ? b16(pt[(size_t)e * IN]) : (short)0;
        }
    }
    const f32x4 c1init = *reinterpret_cast<const f32x4*>(gb1 + d * HID + 16 * w + 4 * q);
    const f32x4 c2init = *reinterpret_cast<const f32x4*>(gb2 + d * HID + 16 * w + 4 * q);
    const f32x4 w3r    = *reinterpret_cast<const f32x4*>(gW3 + d * HID + 16 * w + 4 * q);
    f32x4 w3s;
    #pragma unroll
    for (int e = 0; e < 4; ++e) w3s[e] = 0.01f * w3r[e];
    const float b3v = gb3[d];

    const float* xb = x + (size_t)b * TROW * DIN;
    float lgacc = 0.0f;

    for (int ps = 0; ps < 8; ++ps) {
        const int tbase = ps * 64;
        float d1v[16];   // leaky'(H1pre) for this thread's 16 (row,col) cells

        // ---- GEMM1: H1pre = W1 V + b1 ; H1 = pre * leaky'(pre) -> LDS
        #pragma unroll
        for (int g = 0; g < 4; ++g) {
            const float* xr = xb + (size_t)(tbase + 16 * g + r) * DIN;
            float f0=0,f1=0,f2=0,f3=0,f4=0,f5=0,f6=0,f7=0;
            if constexpr (L == 0) {
                if (q == 0) {                       // yy[8..15]
                    f32x4 u0 = *reinterpret_cast<const f32x4*>(xr + 8);
                    f32x4 u1 = *reinterpret_cast<const f32x4*>(xr + 12);
                    f0=u0[0]; f1=u0[1]; f2=u0[2]; f3=u0[3];
                    f4=u1[0]; f5=u1[1]; f6=u1[2]; f7=u1[3];
                } else if (q == 1) {                // xx[8+d]
                    f0 = xr[DIN + 8 + d];
                }
            } else {
                if (q == 0) {                       // yy[0..7]
                    f32x4 u0 = *reinterpret_cast<const f32x4*>(xr);
                    f32x4 u1 = *reinterpret_cast<const f32x4*>(xr + 4);
                    f0=u0[0]; f1=u0[1]; f2=u0[2]; f3=u0[3];
                    f4=u1[0]; f5=u1[1]; f6=u1[2]; f7=u1[3];
                } else if (q == 1) {                // xx[8..15]
                    f32x4 u0 = *reinterpret_cast<const f32x4*>(xr + 24);
                    f32x4 u1 = *reinterpret_cast<const f32x4*>(xr + 28);
                    f0=u0[0]; f1=u0[1]; f2=u0[2]; f3=u0[3];
                    f4=u1[0]; f5=u1[1]; f6=u1[2]; f7=u1[3];
                } else if (q == 2) {                // xx[d]
                    f0 = xr[DIN + d];
                }
            }
            bf16x8 bv = mkfrag(pk2(f0,f1), pk2(f2,f3), pk2(f4,f5), pk2(f6,f7));
            f32x4 acc = mfma16(aW1, bv, c1init);
            float hh[4];
            #pragma unroll
            for (int e = 0; e < 4; ++e) {
                float dd = (acc[e] >= 0.0f) ? 1.0f : 0.01f;
                d1v[g * 4 + e] = dd;
                hh[e] = acc[e] * dd;
            }
            *reinterpret_cast<u32x2*>(fr + wbase + g * 256) =
                u32x2{pk2(hh[0], hh[1]), pk2(hh[2], hh[3])};
        }
        __syncthreads();

        // ---- GEMM2: H2pre = W2 H1 + b2 ; residual partial + U2 = D2.W3^T -> LDS
        #pragma unroll
        for (int g = 0; g < 4; ++g) {
            f32x4 acc = c2init;
            acc = mfma16(aW2[0], *reinterpret_cast<const bf16x8*>(fr + rbase + g*256), acc);
            acc = mfma16(aW2[1], *reinterpret_cast<const bf16x8*>(fr + rbase + 4096 + g*256), acc);
            float pr = 0.0f, u2v[4];
            #pragma unroll
            for (int e = 0; e < 4; ++e) {
                u2v[e] = (acc[e] >= 0.0f) ? w3r[e] : w3s[e];   // w3*leaky'
                pr = fmaf(u2v[e], acc[e], pr);                 // w3*h2 == u2*pre
            }
            pr += __shfl_xor(pr, 16, 64);
            pr += __shfl_xor(pr, 32, 64);
            if (q == 0) sm.sresW[w * 64 + 16 * g + r] = pr;
            *reinterpret_cast<u32x2*>(fr + 8192 + wbase + g * 256) =
                u32x2{pk2(u2v[0], u2v[1]), pk2(u2v[2], u2v[3])};
        }
        __syncthreads();

        // ---- GEMM3: U1 = W2^T U2 ; mask by d1 -> LDS
        #pragma unroll
        for (int g = 0; g < 4; ++g) {
            f32x4 acc = {0.0f, 0.0f, 0.0f, 0.0f};
            acc = mfma16(aW2T[0], *reinterpret_cast<const bf16x8*>(fr + 8192 + rbase + g*256), acc);
            acc = mfma16(aW2T[1], *reinterpret_cast<const bf16x8*>(fr + 8192 + rbase + 4096 + g*256), acc);
            float u0 = acc[0] * d1v[g*4+0], u1 = acc[1] * d1v[g*4+1];
            float u2 = acc[2] * d1v[g*4+2], u3 = acc[3] * d1v[g*4+3];
            *reinterpret_cast<u32x2*>(fr + 16384 + wbase + g * 256) =
                u32x2{pk2(u0, u1), pk2(u2, u3)};
        }
        __syncthreads();

        // ---- GEMM4 (N-split: wave w owns samples n=16w+r): G = W1^T (D1.U1)
        {
            const size_t nglob = (size_t)b * NT + tbase + 16 * w + r;
            bf16x8 bu0 = *reinterpret_cast<const bf16x8*>(fr + 16384 + rbase + w * 256);
            bf16x8 bu1 = *reinterpret_cast<const bf16x8*>(fr + 16384 + rbase + 4096 + w * 256);
            f32x4 g0 = {0.0f, 0.0f, 0.0f, 0.0f};
            g0 = mfma16(aW1T[0][0], bu0, g0);
            g0 = mfma16(aW1T[0][1], bu1, g0);
            if constexpr (L == 1) {
                f32x4 g1 = {0.0f, 0.0f, 0.0f, 0.0f};
                g1 = mfma16(aW1T[1][0], bu0, g1);
                g1 = mfma16(aW1T[1][1], bu1, g1);
                *reinterpret_cast<f32x4*>(out + OFF_H1 + ((size_t)d * NSAMP + nglob) * 16 + 4 * q) = g0;
                if (q == 0) lgacc += logf(fabsf(g1[0]));       // row 16 = xcol
            } else {
                if (q < 2)
                    *reinterpret_cast<f32x4*>(out + OFF_H0 + ((size_t)d * NSAMP + nglob) * 8 + 4 * q) = g0;
                if (q == 2) lgacc += logf(fabsf(g0[0]));       // row 8 = xcol
            }
        }
        // ---- residual store (sresW complete since barrier 2)
        if (tid < 64) {
            float rs = sm.sresW[tid] + sm.sresW[64 + tid]
                     + sm.sresW[128 + tid] + sm.sresW[192 + tid] + b3v;
            out[((size_t)b * NT + tbase + tid) * DIN + (L * 8 + d)] = rs;
        }
        // next pass's H1 writes are fenced by its own barrier 1 (all waves must
        // arrive there, which is after every wave's reads of U1/sresW).
    }

    // ---- block epilogue: logdet reduction + one global atomic per block
    float v = lgacc;
    #pragma unroll
    for (int off = 1; off < 64; off <<= 1) v += __shfl_xor(v, off, 64);
    if (lane == 0) sm.slogW[w] = v;
    __syncthreads();
    if (tid == 0)
        atomicAdd(out + OFF_SUMLOG + b,
                  sm.slogW[0] + sm.slogW[1] + sm.slogW[2] + sm.slogW[3]);
}

__global__ void zero_sumlog_kernel(float* __restrict__ out) {
    out[OFF_SUMLOG + threadIdx.x] = 0.0f;
}

__global__ __launch_bounds__(256, 3) void mlp_mfma_kernel(
    const float* __restrict__ x,
    const float* __restrict__ l0W1, const float* __restrict__ l0b1,
    const float* __restrict__ l0W2, const float* __restrict__ l0b2,
    const float* __restrict__ l0W3, const float* __restrict__ l0b3,
    const float* __restrict__ l1W1, const float* __restrict__ l1b1,
    const float* __restrict__ l1W2, const float* __restrict__ l1b2,
    const float* __restrict__ l1W3, const float* __restrict__ l1b3,
    float* __restrict__ out)
{
    __shared__ SMem sm;
    // XCD-aware decode: assuming HW round-robins blockIdx%8 across the 8 XCDs,
    // XCD k owns batch rows [32k, 32k+32) for ALL 16 (L,d) units -> x slice
    // (1 MB) + residual lines + weights fit one L2; x fetched from HBM once.
    const int xcd = blockIdx.x & 7;
    const int idx = blockIdx.x >> 3;         // 0..511
    const int b   = xcd * 32 + (idx & 31);
    const int uld = idx >> 5;                // 0..15
    if (uld < 8)
        mlp_impl<0, 9>(sm, uld, b, x, l0W1, l0b1, l0W2, l0b2, l0W3, l0b3, out);
    else
        mlp_impl<1, 17>(sm, uld - 8, b, x, l1W1, l1b1, l1W2, l1b2, l1W3, l1b3, out);
}

} // namespace

extern "C" void kernel_launch(void* const* d_in, const int* in_sizes, int n_in,
                              void* d_out, int out_size, void* d_ws, size_t ws_size,
                              hipStream_t stream) {
    const float* x = (const float*)d_in[0];
    // d_in[1] = alphas — unused by the reference outputs
    float* out = (float*)d_out;

    zero_sumlog_kernel<<<1, 256, 0, stream>>>(out);
    mlp_mfma_kernel<<<4096, 256, 0, stream>>>(
        x,
        (const float*)d_in[2],  (const float*)d_in[3],  (const float*)d_in[4],
        (const float*)d_in[5],  (const float*)d_in[6],  (const float*)d_in[7],
        (const float*)d_in[8],  (const float*)d_in[9],  (const float*)d_in[10],
        (const float*)d_in[11], (const float*)d_in[12], (const float*)d_in[13],
        out);
}